// Round 5
// baseline (71.972 us; speedup 1.0000x reference)
//
#include <hip/hip_runtime.h>
#include <hip/hip_bf16.h>

#define N_NODES 120000
#define F       64
#define NCHUNK  4           // 4 column-chunks of 16 cols; each chunk = N*16*2B = 3.84 MB < 4 MB per-XCD L2

typedef __attribute__((ext_vector_type(8))) short bf16x8;   // 4 VGPRs
typedef __attribute__((ext_vector_type(4))) float f32x4;    // MFMA C/D

static __device__ __forceinline__ unsigned short f2bf(float x) {
    return __hip_bfloat16_raw(__float2bfloat16(x)).x;   // RNE
}

// Pack theta_w/phi_w into per-lane MFMA B-operand fragments (bf16).
__global__ void prep_weights(const float* __restrict__ theta_w,
                             const float* __restrict__ phi_w,
                             unsigned short* __restrict__ wfrag)  // [16][64][8]
{
    const int t    = threadIdx.x;          // 0..1023
    const int slot = t >> 6, lane = t & 63;
    const int mat  = slot >> 3, c = (slot >> 1) & 3, kb = slot & 1;
    const float* W = mat ? phi_w : theta_w;
    const int k0   = kb * 32 + ((lane >> 4) * 8);
    const int col  = c * 16 + (lane & 15);
    bf16x8 v;
    #pragma unroll
    for (int e = 0; e < 8; ++e)
        v[e] = (short)f2bf(W[(k0 + e) * F + col]);
    ((bf16x8*)wfrag)[slot * 64 + lane] = v;
}

// Kernel 1 (MFMA): Tc[c][r][16] = bf16(feat@theta), Bc[c][r][16] = bf16(T + feat@phi + biases)
// Column-chunked layouts so kernel 2's gather working set fits a per-XCD L2.
__global__ __launch_bounds__(256) void edgeconv_mfma(
    const float* __restrict__ feat,
    const unsigned short* __restrict__ wfrag,
    const float* __restrict__ theta_b,
    const float* __restrict__ phi_b,
    unsigned short* __restrict__ Tc,   // [4][N][16] bf16
    unsigned short* __restrict__ Bc)   // [4][N][16] bf16
{
    const int lane = threadIdx.x & 63;
    const int wv   = threadIdx.x >> 6;
    const int tile = blockIdx.x * 4 + wv;
    const int r0   = tile * 16;

    const bf16x8* wf = (const bf16x8*)wfrag;
    bf16x8 wt[4][2], wp[4][2];
    #pragma unroll
    for (int c = 0; c < 4; ++c) {
        #pragma unroll
        for (int kb = 0; kb < 2; ++kb) {
            wt[c][kb] = wf[((0 * 4 + c) * 2 + kb) * 64 + lane];
            wp[c][kb] = wf[((1 * 4 + c) * 2 + kb) * 64 + lane];
        }
    }

    const int arow = r0 + (lane & 15);
    const int k0   = (lane >> 4) * 8;
    const float4* f0 = (const float4*)(feat + arow * F + k0);
    const float4* f1 = (const float4*)(feat + arow * F + 32 + k0);
    float4 a0 = f0[0], a1 = f0[1];
    float4 a2 = f1[0], a3 = f1[1];
    bf16x8 afr0, afr1;
    afr0[0]=(short)f2bf(a0.x); afr0[1]=(short)f2bf(a0.y); afr0[2]=(short)f2bf(a0.z); afr0[3]=(short)f2bf(a0.w);
    afr0[4]=(short)f2bf(a1.x); afr0[5]=(short)f2bf(a1.y); afr0[6]=(short)f2bf(a1.z); afr0[7]=(short)f2bf(a1.w);
    afr1[0]=(short)f2bf(a2.x); afr1[1]=(short)f2bf(a2.y); afr1[2]=(short)f2bf(a2.z); afr1[3]=(short)f2bf(a2.w);
    afr1[4]=(short)f2bf(a3.x); afr1[5]=(short)f2bf(a3.y); afr1[6]=(short)f2bf(a3.z); afr1[7]=(short)f2bf(a3.w);

    f32x4 accT[4], accP[4];
    #pragma unroll
    for (int c = 0; c < 4; ++c) { accT[c] = (f32x4)(0.f); accP[c] = (f32x4)(0.f); }

    #pragma unroll
    for (int c = 0; c < 4; ++c) {
        accT[c] = __builtin_amdgcn_mfma_f32_16x16x32_bf16(afr0, wt[c][0], accT[c], 0, 0, 0);
        accT[c] = __builtin_amdgcn_mfma_f32_16x16x32_bf16(afr1, wt[c][1], accT[c], 0, 0, 0);
        accP[c] = __builtin_amdgcn_mfma_f32_16x16x32_bf16(afr0, wp[c][0], accP[c], 0, 0, 0);
        accP[c] = __builtin_amdgcn_mfma_f32_16x16x32_bf16(afr1, wp[c][1], accP[c], 0, 0, 0);
    }

    const int colbase = lane & 15;
    const int rowbase = (lane >> 4) * 4;
    #pragma unroll
    for (int c = 0; c < 4; ++c) {
        const int col  = c * 16 + colbase;
        const float bo = theta_b[col] + phi_b[col];
        #pragma unroll
        for (int rg = 0; rg < 4; ++rg) {
            const int r = r0 + rowbase + rg;
            const float t = accT[c][rg];
            Tc[(c * N_NODES + r) * 16 + colbase] = f2bf(t);
            Bc[(c * N_NODES + r) * 16 + colbase] = f2bf(t + accP[c][rg] + bo);
        }
    }
}

// Kernel 2: out[v][c*16+cc] = Bc[c][v][cc] - min_k Tc[c][nbr[v][k]][cc]
// XCD-pinned chunks: xcd = bid&7 (empirical round-robin), chunk = xcd>>1.
// Each XCD gathers only from its own 3.84 MB chunk -> stays L2-resident.
// Lane layout: 8 lanes per node (2 cols each), 8 nodes per wave, 32 nodes per block.
__global__ __launch_bounds__(256) void edgeconv_minmax(
    const int* __restrict__ nbr,              // [N,16] int32
    const unsigned short* __restrict__ Tc,    // [4][N][16] bf16
    const unsigned short* __restrict__ Bc,    // [4][N][16] bf16
    float* __restrict__ out)                  // [N,64] f32
{
    const int bid   = blockIdx.x;
    const int xcd   = bid & 7;
    const int chunk = xcd >> 1;                       // XCD pair {2c,2c+1} owns chunk c
    const int ng    = (bid >> 3) * 2 + (xcd & 1);     // node-group 0..3749 within chunk

    const int tid  = threadIdx.x;
    const int lane = tid & 63;
    const int wv   = tid >> 6;
    const int sub  = lane >> 3;      // node within wave, 0..7
    const int j    = lane & 7;       // column pair within chunk: cols 2j, 2j+1
    const int v    = ng * 32 + wv * 8 + sub;

    // 16 neighbor indices (8 lanes per node read identical addresses -> broadcast)
    const int4* nb4 = (const int4*)(nbr + v * 16);
    int4 i0 = nb4[0], i1 = nb4[1], i2 = nb4[2], i3 = nb4[3];
    int idx[16] = { i0.x, i0.y, i0.z, i0.w,
                    i1.x, i1.y, i1.z, i1.w,
                    i2.x, i2.y, i2.z, i2.w,
                    i3.x, i3.y, i3.z, i3.w };

    const char* tbase = (const char*)Tc + (size_t)chunk * N_NODES * 32 + (j << 2);

    // 16 independent 4B gathers per lane; per instr: 8 nodes x 32B aligned segments.
    unsigned int u[16];
    #pragma unroll
    for (int k = 0; k < 16; ++k)
        u[k] = *(const unsigned int*)(tbase + (((unsigned int)idx[k]) << 5));

    float mlo = __uint_as_float(u[0] << 16);
    float mhi = __uint_as_float(u[0] & 0xffff0000u);
    #pragma unroll
    for (int k = 1; k < 16; ++k) {
        mlo = fminf(mlo, __uint_as_float(u[k] << 16));
        mhi = fminf(mhi, __uint_as_float(u[k] & 0xffff0000u));
    }

    const unsigned int bu = *(const unsigned int*)(
        (const char*)Bc + (size_t)chunk * N_NODES * 32 + (((unsigned int)v) << 5) + (j << 2));
    const float blo = __uint_as_float(bu << 16);
    const float bhi = __uint_as_float(bu & 0xffff0000u);

    float2 res = make_float2(blo - mlo, bhi - mhi);
    *(float2*)(out + v * F + chunk * 16 + 2 * j) = res;
}

extern "C" void kernel_launch(void* const* d_in, const int* in_sizes, int n_in,
                              void* d_out, int out_size, void* d_ws, size_t ws_size,
                              hipStream_t stream) {
    const float* feat    = (const float*)d_in[0];
    const int*   nbr     = (const int*)  d_in[1];
    const float* theta_w = (const float*)d_in[2];
    const float* theta_b = (const float*)d_in[3];
    const float* phi_w   = (const float*)d_in[4];
    const float* phi_b   = (const float*)d_in[5];
    float* out = (float*)d_out;

    unsigned short* wfrag = (unsigned short*)d_ws;                        // 16 KB
    unsigned short* Tc    = (unsigned short*)((char*)d_ws + 16384);      // 15.36 MB
    unsigned short* Bc    = (unsigned short*)((char*)d_ws + 16384 + 15360000);

    prep_weights<<<1, 1024, 0, stream>>>(theta_w, phi_w, wfrag);
    edgeconv_mfma<<<N_NODES / 64, 256, 0, stream>>>(feat, wfrag, theta_b, phi_b, Tc, Bc);
    // 4 chunks x 3750 node-groups of 32 nodes = 15000 blocks
    edgeconv_minmax<<<15000, 256, 0, stream>>>(nbr, Tc, Bc, out);
}

// Round 6
// 60.268 us; speedup vs baseline: 1.1942x; 1.1942x over previous
//
#include <hip/hip_runtime.h>
#include <hip/hip_bf16.h>

#define N_NODES 120000
#define F       64

typedef __attribute__((ext_vector_type(8))) short bf16x8;   // 4 VGPRs
typedef __attribute__((ext_vector_type(4))) float f32x4;    // MFMA C/D

static __device__ __forceinline__ unsigned short f2bf(float x) {
    return __hip_bfloat16_raw(__float2bfloat16(x)).x;   // RNE
}
static __device__ __forceinline__ float u2f(unsigned int x) {
    return __uint_as_float(x);
}

// Pack theta_w/phi_w into per-lane MFMA B-operand fragments (bf16).
__global__ void prep_weights(const float* __restrict__ theta_w,
                             const float* __restrict__ phi_w,
                             unsigned short* __restrict__ wfrag)  // [16][64][8]
{
    const int t    = threadIdx.x;          // 0..1023
    const int slot = t >> 6, lane = t & 63;
    const int mat  = slot >> 3, c = (slot >> 1) & 3, kb = slot & 1;
    const float* W = mat ? phi_w : theta_w;
    const int k0   = kb * 32 + ((lane >> 4) * 8);
    const int col  = c * 16 + (lane & 15);
    bf16x8 v;
    #pragma unroll
    for (int e = 0; e < 8; ++e)
        v[e] = (short)f2bf(W[(k0 + e) * F + col]);
    ((bf16x8*)wfrag)[slot * 64 + lane] = v;
}

// Kernel 1 (MFMA): T16 = bf16(feat@theta); B16 = bf16(T + feat@phi + biases)
__global__ __launch_bounds__(256) void edgeconv_mfma(
    const float* __restrict__ feat,
    const unsigned short* __restrict__ wfrag,
    const float* __restrict__ theta_b,
    const float* __restrict__ phi_b,
    unsigned short* __restrict__ T16,
    unsigned short* __restrict__ B16)
{
    const int lane = threadIdx.x & 63;
    const int wv   = threadIdx.x >> 6;
    const int tile = blockIdx.x * 4 + wv;
    const int r0   = tile * 16;

    const bf16x8* wf = (const bf16x8*)wfrag;
    bf16x8 wt[4][2], wp[4][2];
    #pragma unroll
    for (int c = 0; c < 4; ++c) {
        #pragma unroll
        for (int kb = 0; kb < 2; ++kb) {
            wt[c][kb] = wf[((0 * 4 + c) * 2 + kb) * 64 + lane];
            wp[c][kb] = wf[((1 * 4 + c) * 2 + kb) * 64 + lane];
        }
    }

    const int arow = r0 + (lane & 15);
    const int k0   = (lane >> 4) * 8;
    const float4* f0 = (const float4*)(feat + arow * F + k0);
    const float4* f1 = (const float4*)(feat + arow * F + 32 + k0);
    float4 a0 = f0[0], a1 = f0[1];
    float4 a2 = f1[0], a3 = f1[1];
    bf16x8 afr0, afr1;
    afr0[0]=(short)f2bf(a0.x); afr0[1]=(short)f2bf(a0.y); afr0[2]=(short)f2bf(a0.z); afr0[3]=(short)f2bf(a0.w);
    afr0[4]=(short)f2bf(a1.x); afr0[5]=(short)f2bf(a1.y); afr0[6]=(short)f2bf(a1.z); afr0[7]=(short)f2bf(a1.w);
    afr1[0]=(short)f2bf(a2.x); afr1[1]=(short)f2bf(a2.y); afr1[2]=(short)f2bf(a2.z); afr1[3]=(short)f2bf(a2.w);
    afr1[4]=(short)f2bf(a3.x); afr1[5]=(short)f2bf(a3.y); afr1[6]=(short)f2bf(a3.z); afr1[7]=(short)f2bf(a3.w);

    f32x4 accT[4], accP[4];
    #pragma unroll
    for (int c = 0; c < 4; ++c) { accT[c] = (f32x4)(0.f); accP[c] = (f32x4)(0.f); }

    #pragma unroll
    for (int c = 0; c < 4; ++c) {
        accT[c] = __builtin_amdgcn_mfma_f32_16x16x32_bf16(afr0, wt[c][0], accT[c], 0, 0, 0);
        accT[c] = __builtin_amdgcn_mfma_f32_16x16x32_bf16(afr1, wt[c][1], accT[c], 0, 0, 0);
        accP[c] = __builtin_amdgcn_mfma_f32_16x16x32_bf16(afr0, wp[c][0], accP[c], 0, 0, 0);
        accP[c] = __builtin_amdgcn_mfma_f32_16x16x32_bf16(afr1, wp[c][1], accP[c], 0, 0, 0);
    }

    const int colbase = lane & 15;
    const int rowbase = (lane >> 4) * 4;
    #pragma unroll
    for (int c = 0; c < 4; ++c) {
        const int col  = c * 16 + colbase;
        const float bo = theta_b[col] + phi_b[col];
        #pragma unroll
        for (int rg = 0; rg < 4; ++rg) {
            const int r = r0 + rowbase + rg;
            const float t = accT[c][rg];
            T16[r * F + col] = f2bf(t);
            B16[r * F + col] = f2bf(t + accP[c][rg] + bo);
        }
    }
}

// Kernel 2: out[v][o] = B[v][o] - min_k T[nbr[v][k]][o]
// 8 nodes/wave, 8 lanes/node, uint4 (16B) gathers -> each instruction requests
// 8 random 128B rows; 16 KB in flight per wave (max MLP at full-line granularity).
// bf16 trick: raw dword's high half IS an f32 (garbage low mantissa <= 2^-8 rel),
// so odd columns need no shift/mask in the fmin chain.
__global__ __launch_bounds__(256) void edgeconv_minmax(
    const int* __restrict__ nbr,              // [N,16] int32
    const unsigned short* __restrict__ T16,   // [N,64] bf16
    const unsigned short* __restrict__ B16,   // [N,64] bf16
    float* __restrict__ out)                  // [N,64] f32
{
    const int tid  = threadIdx.x;
    const int lane = tid & 63;
    const int wv   = tid >> 6;
    const int sub  = lane >> 3;      // node within wave, 0..7
    const int j    = lane & 7;       // lane covers cols 8j..8j+7 (16B)
    const int v    = blockIdx.x * 32 + wv * 8 + sub;

    // 16 neighbor indices (8 lanes per node read identical addresses -> broadcast)
    const int4* nb4 = (const int4*)(nbr + v * 16);
    int4 i0 = nb4[0], i1 = nb4[1], i2 = nb4[2], i3 = nb4[3];
    int idx[16] = { i0.x, i0.y, i0.z, i0.w,
                    i1.x, i1.y, i1.z, i1.w,
                    i2.x, i2.y, i2.z, i2.w,
                    i3.x, i3.y, i3.z, i3.w };

    const char* tb = (const char*)T16 + (j << 4);

    // 16 independent 16B gathers per lane (all issued before consumption).
    uint4 u[16];
    #pragma unroll
    for (int k = 0; k < 16; ++k)
        u[k] = *(const uint4*)(tb + (((unsigned int)idx[k]) << 7));

    // 8 running mins: even cols via <<16, odd cols via raw-as-f32.
    float mn[8];
    mn[0] = u2f(u[0].x << 16); mn[1] = u2f(u[0].x);
    mn[2] = u2f(u[0].y << 16); mn[3] = u2f(u[0].y);
    mn[4] = u2f(u[0].z << 16); mn[5] = u2f(u[0].z);
    mn[6] = u2f(u[0].w << 16); mn[7] = u2f(u[0].w);
    #pragma unroll
    for (int k = 1; k < 16; ++k) {
        mn[0] = fminf(mn[0], u2f(u[k].x << 16)); mn[1] = fminf(mn[1], u2f(u[k].x));
        mn[2] = fminf(mn[2], u2f(u[k].y << 16)); mn[3] = fminf(mn[3], u2f(u[k].y));
        mn[4] = fminf(mn[4], u2f(u[k].z << 16)); mn[5] = fminf(mn[5], u2f(u[k].z));
        mn[6] = fminf(mn[6], u2f(u[k].w << 16)); mn[7] = fminf(mn[7], u2f(u[k].w));
    }

    const uint4 bu = *(const uint4*)((const char*)B16 + (((unsigned int)v) << 7) + (j << 4));
    float4 r0, r1;
    r0.x = u2f(bu.x << 16)        - mn[0];
    r0.y = u2f(bu.x & 0xffff0000u) - mn[1];
    r0.z = u2f(bu.y << 16)        - mn[2];
    r0.w = u2f(bu.y & 0xffff0000u) - mn[3];
    r1.x = u2f(bu.z << 16)        - mn[4];
    r1.y = u2f(bu.z & 0xffff0000u) - mn[5];
    r1.z = u2f(bu.w << 16)        - mn[6];
    r1.w = u2f(bu.w & 0xffff0000u) - mn[7];

    float* op = out + v * F + j * 8;
    *(float4*)op       = r0;
    *(float4*)(op + 4) = r1;
}

extern "C" void kernel_launch(void* const* d_in, const int* in_sizes, int n_in,
                              void* d_out, int out_size, void* d_ws, size_t ws_size,
                              hipStream_t stream) {
    const float* feat    = (const float*)d_in[0];
    const int*   nbr     = (const int*)  d_in[1];
    const float* theta_w = (const float*)d_in[2];
    const float* theta_b = (const float*)d_in[3];
    const float* phi_w   = (const float*)d_in[4];
    const float* phi_b   = (const float*)d_in[5];
    float* out = (float*)d_out;

    unsigned short* wfrag = (unsigned short*)d_ws;                        // 16 KB
    unsigned short* T16   = (unsigned short*)((char*)d_ws + 16384);      // 15.36 MB
    unsigned short* B16   = (unsigned short*)((char*)d_ws + 16384 + 15360000);

    prep_weights<<<1, 1024, 0, stream>>>(theta_w, phi_w, wfrag);
    edgeconv_mfma<<<N_NODES / 64, 256, 0, stream>>>(feat, wfrag, theta_b, phi_b, T16, B16);
    edgeconv_minmax<<<N_NODES / 32, 256, 0, stream>>>(nbr, T16, B16, out);
}